// Round 1
// baseline (141.649 us; speedup 1.0000x reference)
//
#include <hip/hip_runtime.h>
#include <stdint.h>

#define DD 512
#define NP 1024        // 32*32 positions
#define NBATCH 16
#define BM 128
#define BN 128
#define BK 32
#define LDS_STRIDE 40  // BK + 8 pad (in shorts) -> 80B row stride, 16B aligned

typedef __attribute__((ext_vector_type(8))) __bf16 bf16x8;
typedef __attribute__((ext_vector_type(4))) float f32x4;
typedef __attribute__((ext_vector_type(4))) unsigned short u16x4;

__device__ __forceinline__ unsigned short f2bf(float f) {
    union { float f; uint32_t u; } v; v.f = f;
    uint32_t u = v.u;
    return (unsigned short)((u + 0x7FFFu + ((u >> 16) & 1u)) >> 16);
}

__global__ __launch_bounds__(256) void pe2d_gemm(
    const float* __restrict__ q,      // [B][NP][D]
    const float* __restrict__ kin,    // [B][NP][D]
    const float* __restrict__ embed,  // [NP][D]
    float* __restrict__ out)          // [B][NP][NP]
{
    __shared__ unsigned short Alds[BM * LDS_STRIDE];
    __shared__ unsigned short Blds[BN * LDS_STRIDE];

    const int tid = threadIdx.x;
    const int b = blockIdx.y;
    const int tileP = blockIdx.x >> 3;
    const int tileQ = blockIdx.x & 7;
    const int P0 = tileP * BM, Q0 = tileQ * BN;

    const int lane = tid & 63;
    const int wid = tid >> 6;           // 0..3
    const int wm = wid >> 1, wn = wid & 1;
    const int lr = lane & 15;           // row (A) / col (B) within fragment
    const int ko = (lane >> 4) * 8;     // k offset within BK

    f32x4 acc[4][4];
    #pragma unroll
    for (int i = 0; i < 4; ++i)
        #pragma unroll
        for (int j = 0; j < 4; ++j)
            acc[i][j] = (f32x4)0.0f;

    for (int phase = 0; phase < 2; ++phase) {
        const float* Asrc = (phase == 0) ? (q + (size_t)b * NP * DD) : embed;
        const float* Bsrc = (phase == 0) ? embed : (kin + (size_t)b * NP * DD);
        const bool   addE = (phase == 1);

        for (int kt = 0; kt < DD; kt += BK) {
            __syncthreads();   // previous step's reads done before overwrite
            // stage A and B tiles: each 128 rows x 32 f32 -> bf16 in LDS
            #pragma unroll
            for (int it = 0; it < 4; ++it) {
                int flat = it * 256 + tid;   // 0..1023
                int row  = flat >> 3;
                int c4   = (flat & 7) * 4;
                const float4 va = *(const float4*)(Asrc + (size_t)(P0 + row) * DD + kt + c4);
                float4 vb = *(const float4*)(Bsrc + (size_t)(Q0 + row) * DD + kt + c4);
                if (addE) {
                    const float4 ve = *(const float4*)(embed + (size_t)(Q0 + row) * DD + kt + c4);
                    vb.x += ve.x; vb.y += ve.y; vb.z += ve.z; vb.w += ve.w;
                }
                u16x4 wa; wa.x = f2bf(va.x); wa.y = f2bf(va.y); wa.z = f2bf(va.z); wa.w = f2bf(va.w);
                u16x4 wb; wb.x = f2bf(vb.x); wb.y = f2bf(vb.y); wb.z = f2bf(vb.z); wb.w = f2bf(vb.w);
                *(u16x4*)&Alds[row * LDS_STRIDE + c4] = wa;
                *(u16x4*)&Blds[row * LDS_STRIDE + c4] = wb;
            }
            __syncthreads();

            bf16x8 af[4], bfr[4];
            #pragma unroll
            for (int mi = 0; mi < 4; ++mi)
                af[mi] = *(const bf16x8*)&Alds[(wm * 64 + mi * 16 + lr) * LDS_STRIDE + ko];
            #pragma unroll
            for (int ni = 0; ni < 4; ++ni)
                bfr[ni] = *(const bf16x8*)&Blds[(wn * 64 + ni * 16 + lr) * LDS_STRIDE + ko];
            #pragma unroll
            for (int mi = 0; mi < 4; ++mi)
                #pragma unroll
                for (int ni = 0; ni < 4; ++ni)
                    acc[mi][ni] = __builtin_amdgcn_mfma_f32_16x16x32_bf16(
                        af[mi], bfr[ni], acc[mi][ni], 0, 0, 0);
        }
    }

    // epilogue: C/D layout col=lane&15, row=(lane>>4)*4+reg  [m89-verified]
    float* outb = out + (size_t)b * NP * NP;
    #pragma unroll
    for (int mi = 0; mi < 4; ++mi) {
        #pragma unroll
        for (int ni = 0; ni < 4; ++ni) {
            int col  = Q0 + wn * 64 + ni * 16 + lr;
            int row0 = P0 + wm * 64 + mi * 16 + (lane >> 4) * 4;
            #pragma unroll
            for (int i = 0; i < 4; ++i)
                outb[(size_t)(row0 + i) * NP + col] = acc[mi][ni][i];
        }
    }
}

extern "C" void kernel_launch(void* const* d_in, const int* in_sizes, int n_in,
                              void* d_out, int out_size, void* d_ws, size_t ws_size,
                              hipStream_t stream) {
    const float* q  = (const float*)d_in[0];
    const float* k  = (const float*)d_in[1];
    const float* e  = (const float*)d_in[2];
    float* out = (float*)d_out;
    dim3 grid(64, NBATCH), block(256);
    hipLaunchKernelGGL(pe2d_gemm, grid, block, 0, stream, q, k, e, out);
}

// Round 2
// 68.094 us; speedup vs baseline: 2.0802x; 2.0802x over previous
//
#include <hip/hip_runtime.h>
#include <stdint.h>

#define DD 512
#define NP 1024        // 32*32 positions
#define NBATCH 16

#define QELEMS (NBATCH * NP * DD)   // 8388608
#define EELEMS (NP * DD)            // 524288
#define QVEC   (QELEMS / 8)         // 1048576
#define EVEC   (EELEMS / 8)         // 65536
#define TOTVEC (2 * QVEC + EVEC)    // 2162688

typedef __attribute__((ext_vector_type(8))) __bf16 bf16x8;
typedef __attribute__((ext_vector_type(4))) float f32x4;
typedef __attribute__((ext_vector_type(8))) unsigned short u16x8;

__device__ __forceinline__ unsigned short f2bf(float f) {
    union { float f; uint32_t u; } v; v.f = f;
    uint32_t u = v.u;
    return (unsigned short)((u + 0x7FFFu + ((u >> 16) & 1u)) >> 16);
}

// ---------------- pass 1: f32 -> bf16 convert (+ k+E fuse) ----------------
__global__ __launch_bounds__(256) void convert_pack(
    const float* __restrict__ q, const float* __restrict__ k,
    const float* __restrict__ e,
    unsigned short* __restrict__ qbf, unsigned short* __restrict__ kEbf,
    unsigned short* __restrict__ ebf)
{
    int v = blockIdx.x * 256 + threadIdx.x;
    if (v >= TOTVEC) return;
    const float* src; unsigned short* dst; const float* add = nullptr;
    if (v < QVEC) {
        size_t off = (size_t)v * 8; src = q + off; dst = qbf + off;
    } else if (v < 2 * QVEC) {
        size_t off = (size_t)(v - QVEC) * 8; src = k + off; dst = kEbf + off;
        add = e + (off & (EELEMS - 1));
    } else {
        size_t off = (size_t)(v - 2 * QVEC) * 8; src = e + off; dst = ebf + off;
    }
    float4 a = *(const float4*)src;
    float4 c = *(const float4*)(src + 4);
    if (add) {
        float4 e0 = *(const float4*)add, e1 = *(const float4*)(add + 4);
        a.x += e0.x; a.y += e0.y; a.z += e0.z; a.w += e0.w;
        c.x += e1.x; c.y += e1.y; c.z += e1.z; c.w += e1.w;
    }
    u16x8 r;
    r[0] = f2bf(a.x); r[1] = f2bf(a.y); r[2] = f2bf(a.z); r[3] = f2bf(a.w);
    r[4] = f2bf(c.x); r[5] = f2bf(c.y); r[6] = f2bf(c.z); r[7] = f2bf(c.w);
    *(u16x8*)dst = r;
}

// ---------------- pass 2: bf16 MFMA GEMM ----------------
// logits[b] = [q[b] | E] . [E | k[b]+E]^T  (K = 1024, two halves of 512)
__device__ __forceinline__ void gload_lds16(const void* g, void* l) {
    __builtin_amdgcn_global_load_lds(
        (const __attribute__((address_space(1))) unsigned int*)g,
        (__attribute__((address_space(3))) unsigned int*)l,
        16, 0, 0);
}

__global__ __launch_bounds__(256) void pe2d_mm(
    const unsigned short* __restrict__ qbf,
    const unsigned short* __restrict__ kEbf,
    const unsigned short* __restrict__ ebf,
    float* __restrict__ out)
{
    __shared__ unsigned short Alds[128 * 64];   // 16 KB, row-major [128][64]
    __shared__ unsigned short Blds[128 * 64];

    const int tid  = threadIdx.x;
    const int lane = tid & 63;
    const int wid  = tid >> 6;                  // 0..3
    const int b    = blockIdx.x >> 6;
    const int tile = blockIdx.x & 63;
    const int P0 = (tile >> 3) * 128, Q0 = (tile & 7) * 128;
    const int wm = wid >> 1, wn = wid & 1;
    const int lr = lane & 15;
    const int ko = (lane >> 4) * 8;             // k offset (elems) within 32

    // staging: lane covers row srow of an 8-row chunk; source col pre-swizzled
    // so linear LDS dest + swizzled ds_read form the same involution (rule 21)
    const int srow = lane >> 3;                        // 0..7
    const int scol = ((lane & 7) ^ srow) << 3;         // elems (16B units)

    f32x4 acc[4][4];
    #pragma unroll
    for (int i = 0; i < 4; ++i)
        #pragma unroll
        for (int j = 0; j < 4; ++j) acc[i][j] = (f32x4)0.0f;

    for (int half = 0; half < 2; ++half) {
        const unsigned short* Asrc = half ? ebf : qbf + (size_t)b * NP * DD;
        const unsigned short* Bsrc = half ? kEbf + (size_t)b * NP * DD : ebf;

        for (int kt = 0; kt < DD; kt += 64) {
            __syncthreads();
            #pragma unroll
            for (int c = 0; c < 4; ++c) {
                const int rowbase = wid * 32 + c * 8;
                const unsigned short* ga =
                    Asrc + (size_t)(P0 + rowbase + srow) * DD + kt + scol;
                const unsigned short* gb =
                    Bsrc + (size_t)(Q0 + rowbase + srow) * DD + kt + scol;
                gload_lds16(ga, &Alds[rowbase * 64]);
                gload_lds16(gb, &Blds[rowbase * 64]);
            }
            __syncthreads();

            #pragma unroll
            for (int kk = 0; kk < 64; kk += 32) {
                bf16x8 af[4], bfr[4];
                #pragma unroll
                for (int mi = 0; mi < 4; ++mi) {
                    const int r = wm * 64 + mi * 16 + lr;
                    const int cby = (kk + ko) * 2;
                    af[mi] = *(const bf16x8*)((const char*)Alds + r * 128 +
                                              (cby ^ ((r & 7) << 4)));
                }
                #pragma unroll
                for (int ni = 0; ni < 4; ++ni) {
                    const int r = wn * 64 + ni * 16 + lr;
                    const int cby = (kk + ko) * 2;
                    bfr[ni] = *(const bf16x8*)((const char*)Blds + r * 128 +
                                               (cby ^ ((r & 7) << 4)));
                }
                #pragma unroll
                for (int mi = 0; mi < 4; ++mi)
                    #pragma unroll
                    for (int ni = 0; ni < 4; ++ni)
                        acc[mi][ni] = __builtin_amdgcn_mfma_f32_16x16x32_bf16(
                            af[mi], bfr[ni], acc[mi][ni], 0, 0, 0);
            }
        }
    }

    // epilogue: C/D layout col=lane&15, row=(lane>>4)*4+reg
    float* outb = out + (size_t)b * NP * NP;
    #pragma unroll
    for (int mi = 0; mi < 4; ++mi) {
        #pragma unroll
        for (int ni = 0; ni < 4; ++ni) {
            const int col  = Q0 + wn * 64 + ni * 16 + lr;
            const int row0 = P0 + wm * 64 + mi * 16 + (lane >> 4) * 4;
            #pragma unroll
            for (int i = 0; i < 4; ++i)
                outb[(size_t)(row0 + i) * NP + col] = acc[mi][ni][i];
        }
    }
}

extern "C" void kernel_launch(void* const* d_in, const int* in_sizes, int n_in,
                              void* d_out, int out_size, void* d_ws, size_t ws_size,
                              hipStream_t stream) {
    const float* q = (const float*)d_in[0];
    const float* k = (const float*)d_in[1];
    const float* e = (const float*)d_in[2];
    float* out = (float*)d_out;

    unsigned short* qbf  = (unsigned short*)d_ws;                       // 16 MB
    unsigned short* kEbf = qbf + (size_t)QELEMS;                        // 16 MB
    unsigned short* ebf  = kEbf + (size_t)QELEMS;                       // 1 MB

    hipLaunchKernelGGL(convert_pack, dim3((TOTVEC + 255) / 256), dim3(256),
                       0, stream, q, k, e, qbf, kEbf, ebf);
    hipLaunchKernelGGL(pe2d_mm, dim3(64 * NBATCH), dim3(256), 0, stream,
                       qbf, kEbf, ebf, out);
}

// Round 3
// 50.621 us; speedup vs baseline: 2.7982x; 1.3452x over previous
//
#include <hip/hip_runtime.h>
#include <stdint.h>

#define DD 512
#define NP 1024
#define NB 16

typedef __attribute__((ext_vector_type(8))) __bf16 bf16x8;
typedef __attribute__((ext_vector_type(4))) float f32x4;

// ---------------- kernel 1: thin GEMMs vs EHW (rank-64 factor matrix) ----
// EHW rows 0..31  = eh'[i] = embed[i*32]          (embed flat [1024][512])
// EHW rows 32..63 = ew'[j] = embed[j] - embed[0]
// G1 (blocks 0..255):  qhw[b*NP+P][m] = q[b,P,:]·EHW[m,:]      (M=16384,N=64)
// G2 (blocks 256..511): khw[b][m][Q] = EHW[m,:]·(k[b,Q,:]+E[Q,:])
__global__ __launch_bounds__(256) void thin_gemm(
    const float* __restrict__ q, const float* __restrict__ kin,
    const float* __restrict__ embed,
    float* __restrict__ qhw, float* __restrict__ khw)
{
    __shared__ __align__(16) unsigned short EHW[64 * 512];  // 64 KB, swizzled

    const int tid  = threadIdx.x;
    const int lane = tid & 63;
    const int wid  = tid >> 6;

    // ---- stage EHW once: f32 -> bf16, XOR-swizzled rows ----
    #pragma unroll
    for (int it = 0; it < 16; ++it) {
        int flat = it * 2048 + tid * 8;
        int row = flat >> 9, col = flat & 511;
        int srcrow = (row < 32) ? (row << 5) : (row - 32);
        const float* sp = embed + (size_t)srcrow * DD + col;
        float4 a = *(const float4*)sp;
        float4 c = *(const float4*)(sp + 4);
        if (row >= 32) {
            float4 z0 = *(const float4*)(embed + col);
            float4 z1 = *(const float4*)(embed + col + 4);
            a.x -= z0.x; a.y -= z0.y; a.z -= z0.z; a.w -= z0.w;
            c.x -= z1.x; c.y -= z1.y; c.z -= z1.z; c.w -= z1.w;
        }
        bf16x8 r;
        r[0] = (__bf16)a.x; r[1] = (__bf16)a.y; r[2] = (__bf16)a.z; r[3] = (__bf16)a.w;
        r[4] = (__bf16)c.x; r[5] = (__bf16)c.y; r[6] = (__bf16)c.z; r[7] = (__bf16)c.w;
        int byte = (col * 2) ^ ((row & 7) << 4);
        *(bf16x8*)((char*)EHW + row * 1024 + byte) = r;
    }
    __syncthreads();   // only barrier in the kernel; EHW read-only after

    const int g2 = (blockIdx.x >= 256) ? 1 : 0;
    const int lr = lane & 15;
    const int kq = (lane >> 4) * 8;

    const float* srcA;
    const float* srcE = nullptr;
    if (!g2) {
        srcA = q + (size_t)(blockIdx.x * 64 + wid * 16 + lr) * DD;
    } else {
        int idx = blockIdx.x - 256;
        int b = idx >> 4, qt = idx & 15;
        int Qrow = qt * 64 + wid * 16 + lr;
        srcA = kin + ((size_t)b * NP + Qrow) * DD;
        srcE = embed + (size_t)Qrow * DD;
    }

    f32x4 acc[4];
    #pragma unroll
    for (int n = 0; n < 4; ++n) acc[n] = (f32x4)0.0f;

    #pragma unroll 4
    for (int kk = 0; kk < DD; kk += 32) {
        // streamed operand: f32 global -> bf16 frag in reg (fused convert)
        float4 a0 = *(const float4*)(srcA + kk + kq);
        float4 a1 = *(const float4*)(srcA + kk + kq + 4);
        if (g2) {
            float4 e0 = *(const float4*)(srcE + kk + kq);
            float4 e1 = *(const float4*)(srcE + kk + kq + 4);
            a0.x += e0.x; a0.y += e0.y; a0.z += e0.z; a0.w += e0.w;
            a1.x += e1.x; a1.y += e1.y; a1.z += e1.z; a1.w += e1.w;
        }
        bf16x8 sf;
        sf[0]=(__bf16)a0.x; sf[1]=(__bf16)a0.y; sf[2]=(__bf16)a0.z; sf[3]=(__bf16)a0.w;
        sf[4]=(__bf16)a1.x; sf[5]=(__bf16)a1.y; sf[6]=(__bf16)a1.z; sf[7]=(__bf16)a1.w;
        bf16x8 ef[4];
        #pragma unroll
        for (int n = 0; n < 4; ++n) {
            int row = n * 16 + lr;
            int byte = ((kk + kq) * 2) ^ ((row & 7) << 4);
            ef[n] = *(const bf16x8*)((const char*)EHW + row * 1024 + byte);
        }
        if (!g2) {
            #pragma unroll
            for (int n = 0; n < 4; ++n)
                acc[n] = __builtin_amdgcn_mfma_f32_16x16x32_bf16(sf, ef[n], acc[n], 0, 0, 0);
        } else {
            #pragma unroll
            for (int n = 0; n < 4; ++n)
                acc[n] = __builtin_amdgcn_mfma_f32_16x16x32_bf16(ef[n], sf, acc[n], 0, 0, 0);
        }
    }

    // C/D layout: col = lane&15, row = (lane>>4)*4 + reg
    if (!g2) {
        float* o = qhw + (size_t)(blockIdx.x * 64 + wid * 16 + (lane >> 4) * 4) * 64;
        #pragma unroll
        for (int n = 0; n < 4; ++n)
            #pragma unroll
            for (int i = 0; i < 4; ++i)
                o[(size_t)i * 64 + n * 16 + lr] = acc[n][i];
    } else {
        int idx = blockIdx.x - 256;
        int b = idx >> 4, qt = idx & 15;
        float* o = khw + (size_t)b * 64 * NP + qt * 64 + wid * 16 + lr;
        #pragma unroll
        for (int n = 0; n < 4; ++n) {
            int m = n * 16 + (lane >> 4) * 4;
            #pragma unroll
            for (int i = 0; i < 4; ++i)
                o[(size_t)(m + i) * NP] = acc[n][i];
        }
    }
}

// ---------------- kernel 2: broadcast assembly (write-BW bound) ----------
// out[b][P=(i,j)][Q=(k,l)] = qhw[b,P][k] + qhw[b,P][32+l]
//                          + khw[b][i][Q] + khw[b][32+j][Q]
__global__ __launch_bounds__(256) void assemble(
    const float* __restrict__ qhw, const float* __restrict__ khw,
    float* __restrict__ out)
{
    __shared__ __align__(16) float kh[NP];
    __shared__ __align__(16) float qq[16 * 64];

    const int tid = threadIdx.x;
    const int b   = blockIdx.x >> 6;
    const int i   = (blockIdx.x >> 1) & 31;
    const int jh  = blockIdx.x & 1;

    ((float4*)kh)[tid] = ((const float4*)(khw + ((size_t)b * 64 + i) * NP))[tid];
    ((float4*)qq)[tid] =
        ((const float4*)(qhw + ((size_t)(b * NP + i * 32 + jh * 16)) * 64))[tid];
    __syncthreads();

    const int Q0 = tid * 4;
    const int kidx = Q0 >> 5;     // k for this float4 (constant within it)
    const int lidx = Q0 & 31;     // l of first element
    const float4 khv = *(const float4*)&kh[Q0];

    float* orow = out + ((size_t)(b * NP + i * 32 + jh * 16)) * NP + Q0;
    const float* kwbase = khw + ((size_t)b * 64 + 32 + jh * 16) * NP + Q0;

    #pragma unroll 4
    for (int jj = 0; jj < 16; ++jj) {
        float4 kw = *(const float4*)(kwbase + (size_t)jj * NP);
        float qh  = qq[jj * 64 + kidx];
        float4 qw = *(const float4*)&qq[jj * 64 + 32 + lidx];
        float4 v;
        v.x = khv.x + kw.x + qh + qw.x;
        v.y = khv.y + kw.y + qh + qw.y;
        v.z = khv.z + kw.z + qh + qw.z;
        v.w = khv.w + kw.w + qh + qw.w;
        *(float4*)(orow + (size_t)jj * NP) = v;
    }
}

extern "C" void kernel_launch(void* const* d_in, const int* in_sizes, int n_in,
                              void* d_out, int out_size, void* d_ws, size_t ws_size,
                              hipStream_t stream) {
    const float* q = (const float*)d_in[0];
    const float* k = (const float*)d_in[1];
    const float* e = (const float*)d_in[2];
    float* out = (float*)d_out;

    float* qhw = (float*)d_ws;                    // [16*1024][64]  = 4 MB
    float* khw = qhw + (size_t)NB * NP * 64;      // [16][64][1024] = 4 MB

    hipLaunchKernelGGL(thin_gemm, dim3(512), dim3(256), 0, stream, q, k, e, qhw, khw);
    hipLaunchKernelGGL(assemble, dim3(1024), dim3(256), 0, stream, qhw, khw, out);
}